// Round 23
// baseline (84.046 us; speedup 1.0000x reference)
//
#include <hip/hip_runtime.h>
#include <hip/hip_bf16.h>
#include <math.h>

#define HIDDEN 512
#define ATTEN  512
#define BATCH  32
#define STEP   2048

#define BM 128                // rows per tile
#define BN 256                // atten cols per tile (2 N-slices)
#define NS (ATTEN / BN)       // 2
#define BK 32                 // K tile
#define NT (HIDDEN / BK)      // 16 K-tiles
#define THREADS 512           // 8 waves: 2(M) x 4(N), wave tile 64x64
#define NTILES (BATCH * (STEP / BM) * NS)   // 1024 work items
#define NBLOCKS 512           // persistent blocks: 2/CU, all resident

#define NCH 32                // s-chunks in weighted-sum kernel
#define CHS (STEP / NCH)      // 64

typedef __attribute__((ext_vector_type(8))) short bf16x8;
typedef __attribute__((ext_vector_type(4))) float f32x4;

// batch_lens may arrive as int64 (reference dtype) or int32 (jax without x64).
// Values >= 1, so int32-view index 1 == 0 iff the buffer is int64.
__device__ __forceinline__ long long load_len(const int* lens_raw, int b) {
    bool is64 = (lens_raw[1] == 0);
    if (is64) return ((const long long*)lens_raw)[b];
    return (long long)lens_raw[b];
}

__device__ __forceinline__ short f2bf(float x) {        // RNE fp32 -> bf16 bits
    unsigned u = __float_as_uint(x);
    unsigned r = (u + 0x7FFFu + ((u >> 16) & 1u)) >> 16;
    return (short)r;
}

// RNE pack of two fp32 -> u32 of 2 bf16 (low half = first arg), HW instr
__device__ __forceinline__ unsigned cvtpk(float lo, float hi) {
    unsigned r;
    asm("v_cvt_pk_bf16_f32 %0, %1, %2" : "=v"(r) : "v"(lo), "v"(hi));
    return r;
}

__device__ __forceinline__ float fast_tanh(float x) {
    float e = __expf(2.0f * x);         // saturates correctly at +-inf
    return 1.0f - 2.0f / (e + 1.0f);
}

// K0: pre-swizzled bf16-HI-only W (R9-proven layout) + work-counter reset.
// Per N-slice ns, K-tile kt: col-pair r2=c>>1 owns a 128B LDS row = 8 slots
// of 16B; slot8 = ((c&1)*4 + s) ^ (r2&7). global chunk n = r2*8 + slot8.
// wglds[((ns*16+kt)*1024 + n)*8 + j], 512 KB total.
__global__ __launch_bounds__(512) void wsplit_kernel(
    const float* __restrict__ W, short* __restrict__ wglds, int* __restrict__ ctr)
{
    if (blockIdx.x == 0 && threadIdx.x == 0) *ctr = 0;   // reset work queue
    int a = blockIdx.x;       // 0..511  (atten col)
    int h = threadIdx.x;      // 0..511  (hidden = k)
    float v = W[(size_t)h * ATTEN + a];
    short hi = f2bf(v);
    int ns = a >> 8, c = a & 255;
    int kt = h >> 5, s = (h >> 3) & 3, j = h & 7;
    int r2 = c >> 1;
    int slot8 = (((c & 1) << 2) | s) ^ (r2 & 7);
    size_t tb = ((size_t)ns * NT + kt) * 1024;
    wglds[(tb + (size_t)r2 * 8 + slot8) * 8 + j] = hi;
}

// K1: persistent-block scores. 512 blocks (2/CU), atomic work queue.
// PURE-DMA one-barrier-per-phase structure (R17-verified sync pattern,
// confound removed): A staged as RAW FP32 directly from X via
// global_load_lds with source-swizzled per-lane addresses (m173 pattern);
// fp32->bf16 conversion in-register at MFMA time via v_cvt_pk_bf16_f32
// (RNE, bit-identical to f2bf). A+B double-buffered, 64 KB LDS.
__global__ __launch_bounds__(THREADS, 4) void scores_mfma_kernel(
    const float* __restrict__ X,        // [B*S*H] fp32
    const int*   __restrict__ lens_raw,
    const short* __restrict__ wglds,    // pre-swizzled bf16-hi W
    const float* __restrict__ bias,
    const float* __restrict__ ctx,
    float* __restrict__ scores_part,    // [NS][B*S]
    int* __restrict__ ctr)
{
    __shared__ char smem[64 * 1024];
    char* const A0 = smem;               // 16 KB each: X fp32, src-swizzled
    char* const A1 = smem + 16 * 1024;
    char* const B0 = smem + 32 * 1024;   // 16 KB each: W-hi, pair-swizzled
    char* const B1 = smem + 48 * 1024;
    __shared__ int widx;

    int t = threadIdx.x;
    int wave = t >> 6, lane = t & 63;
    int wrow = wave >> 2, wcol = wave & 3;      // 2 x 4 wave grid
    int l15 = lane & 15, l4 = lane >> 4;
    int wvuni16 = (t & ~63) * 16;               // wave-uniform LDS byte base

    for (;;) {
        __syncthreads();                 // guards widx + LDS reuse across tiles
        if (t == 0) widx = atomicAdd(ctr, 1);
        __syncthreads();
        int idx = widx;
        if (idx >= NTILES) break;

        int ns = idx & 1;                // ns fastest: consecutive grabs share X
        int mt = idx >> 1;
        int b  = mt >> 4;                // 16 tiles per batch (BM=128)
        int s0 = (mt & 15) * BM;
        long long len = load_len(lens_raw, b);
        if ((long long)s0 >= len) continue;

        int ko = (idx * 7) & (NT - 1);   // K-loop stagger (sum order-free)

        const float* xbase = X + ((size_t)b * STEP + s0) * HIDDEN;
        const short* wbase = wglds + (size_t)ns * NT * 1024 * 8;

        f32x4 acc[4][4];
#pragma unroll
        for (int mi = 0; mi < 4; ++mi)
#pragma unroll
            for (int ni = 0; ni < 4; ++ni)
                acc[mi][ni] = (f32x4){0.f, 0.f, 0.f, 0.f};

// A-DMA for K-tile KG -> LDS buffer SA: 128 rows x 32 fp32 = 16 KB.
// LDS linear slot n = t + i*512 = (row, q); source chunk qg = q ^ (row&7)
// so the READ swizzle (g ^ (row&7)) lands on the right data. Per 8-lane
// group the 8 chunks of one row permute within one 128B segment: coalesced.
#define ADMA(KG, SA)                                                         \
    do {                                                                     \
        _Pragma("unroll")                                                    \
        for (int i = 0; i < 2; ++i) {                                        \
            int n = t + i * 512;                                             \
            int row = n >> 3, q = n & 7;                                     \
            int qg = q ^ (row & 7);                                          \
            const float* g = xbase + (size_t)row * HIDDEN + (KG) * BK + qg * 4; \
            char* l = (SA) + i * 8192 + wvuni16;                             \
            __builtin_amdgcn_global_load_lds(                                \
                (const __attribute__((address_space(1))) unsigned int*)g,    \
                (__attribute__((address_space(3))) unsigned int*)l,          \
                16, 0, 0);                                                   \
        }                                                                    \
    } while (0)

#define BISSUE(KG, SB)                                                       \
    do {                                                                     \
        _Pragma("unroll")                                                    \
        for (int i = 0; i < 2; ++i) {                                        \
            const short* g = wbase + ((size_t)(KG) * 1024 + i * 512 + t) * 8;\
            char* l = (SB) + i * 512 * 16 + wvuni16;                         \
            __builtin_amdgcn_global_load_lds(                                \
                (const __attribute__((address_space(1))) unsigned int*)g,    \
                (__attribute__((address_space(3))) unsigned int*)l,          \
                16, 0, 0);                                                   \
        }                                                                    \
    } while (0)

// 1 term: xh*wh. A read as fp32 (2 x ds_read_b128 per fragment, swizzled
// slots 2*l4 and 2*l4+1), converted in-reg with cvt_pk (RNE).
#define COMPUTE(SA, SB)                                                      \
    do {                                                                     \
        bf16x8 ah[4];                                                        \
        _Pragma("unroll")                                                    \
        for (int mi = 0; mi < 4; ++mi) {                                     \
            int row = wrow * 64 + mi * 16 + l15;                             \
            int rx = row & 7;                                                \
            f32x4 va = *(const f32x4*)((SA) + row * 128                      \
                                       + (((2 * l4) ^ rx) << 4));            \
            f32x4 vb = *(const f32x4*)((SA) + row * 128                      \
                                       + (((2 * l4 + 1) ^ rx) << 4));        \
            unsigned d0 = cvtpk(va[0], va[1]);                               \
            unsigned d1 = cvtpk(va[2], va[3]);                               \
            unsigned d2 = cvtpk(vb[0], vb[1]);                               \
            unsigned d3 = cvtpk(vb[2], vb[3]);                               \
            uint4 u = {d0, d1, d2, d3};                                      \
            ah[mi] = *(bf16x8*)&u;                                           \
        }                                                                    \
        _Pragma("unroll")                                                    \
        for (int ni = 0; ni < 4; ++ni) {                                     \
            int col = wcol * 64 + ni * 16 + l15;                             \
            int r2 = col >> 1;                                               \
            int sl = ((((col & 1) << 2) | l4) ^ (r2 & 7));                   \
            bf16x8 bh = *(const bf16x8*)((SB) + r2 * 128 + (sl << 4));       \
            _Pragma("unroll")                                                \
            for (int mi = 0; mi < 4; ++mi) {                                 \
                acc[mi][ni] = __builtin_amdgcn_mfma_f32_16x16x32_bf16(       \
                    ah[mi], bh, acc[mi][ni], 0, 0, 0);                       \
            }                                                                \
        }                                                                    \
    } while (0)

        // prologue: stage K-tile ko into buf0; barrier drains both DMAs
        ADMA(ko, A0);
        BISSUE(ko, B0);
        __syncthreads();

        // main loop: ISSUE(next -> other buf) BEFORE COMPUTE(cur); ONE
        // barrier per phase drains next-tile DMA and protects buffer swap
        // (buf[other] was last read in phase i-1, behind that barrier).
#pragma unroll
        for (int i = 0; i < NT; ++i) {
            int kn = (ko + i + 1) & (NT - 1);
            if (i + 1 < NT) {
                if (((i + 1) & 1)) { ADMA(kn, A1); BISSUE(kn, B1); }
                else               { ADMA(kn, A0); BISSUE(kn, B0); }
            }
            if ((i & 1) == 0) COMPUTE(A0, B0);
            else              COMPUTE(A1, B1);
            __syncthreads();
        }
#undef ADMA
#undef BISSUE
#undef COMPUTE

        // fused epilogue: tanh(acc+bias)*ctx over this slice's 256 cols.
        // Last COMPUTE (i=15) used A1/B1; A0 free since phase-14 barrier.
        float bi[4], ci[4];
#pragma unroll
        for (int ni = 0; ni < 4; ++ni) {
            int a = ns * BN + wcol * 64 + ni * 16 + l15;
            bi[ni] = bias[a];
            ci[ni] = ctx[a];
        }
        float* partial = (float*)A0;     // [4 wcol][BM]
#pragma unroll
        for (int mi = 0; mi < 4; ++mi) {
#pragma unroll
            for (int reg = 0; reg < 4; ++reg) {
                float s = 0.f;
#pragma unroll
                for (int ni = 0; ni < 4; ++ni)
                    s += fast_tanh(acc[mi][ni][reg] + bi[ni]) * ci[ni];
                s += __shfl_xor(s, 1);
                s += __shfl_xor(s, 2);
                s += __shfl_xor(s, 4);
                s += __shfl_xor(s, 8);
                if (l15 == 0) {
                    int row = wrow * 64 + mi * 16 + l4 * 4 + reg;  // C/D layout
                    partial[wcol * BM + row] = s;
                }
            }
        }
        __syncthreads();
        if (t < BM) {
            float v = partial[0 * BM + t] + partial[1 * BM + t]
                    + partial[2 * BM + t] + partial[3 * BM + t];
            scores_part[((size_t)ns * BATCH + b) * STEP + s0 + t] = v;
        }
    }
}

// K2 (fused softmax + weighted sum): each block recomputes the row softmax
// deterministically (identical reduction tree in every block -> identical
// result), stores exp-weights in LDS, then accumulates its s-chunk.
// partial[b,ch,h] = sum_{s in chunk, s<len} atten[b,s] * X[b,s,h]
__global__ __launch_bounds__(256) void wsum_kernel(
    const float* __restrict__ X, const int* __restrict__ lens_raw,
    const float* __restrict__ p0, const float* __restrict__ p1,
    float* __restrict__ partial)
{
    __shared__ float wmax[4], wsumr[4];
    __shared__ float ex[STEP];          // 8 KB: attention weights
    int ch = blockIdx.x;
    int b  = blockIdx.y;
    long long len = load_len(lens_raw, b);
    int t = threadIdx.x;

    // --- replicated masked softmax (exact tree of the old K2) ---
    const float* r0 = p0 + (size_t)b * STEP;
    const float* r1 = p1 + (size_t)b * STEP;
    float sv[STEP / 256];
    float locmax = -INFINITY;
#pragma unroll
    for (int k = 0; k < 8; ++k) {
        int s = t + k * 256;
        float v = ((long long)s < len) ? (r0[s] + r1[s]) : -INFINITY;
        sv[k] = v;
        locmax = fmaxf(locmax, v);
    }
    for (int o = 1; o < 64; o <<= 1) locmax = fmaxf(locmax, __shfl_xor(locmax, o));
    int wave = t >> 6, lane = t & 63;
    if (lane == 0) wmax[wave] = locmax;
    __syncthreads();
    float gmax = fmaxf(fmaxf(wmax[0], wmax[1]), fmaxf(wmax[2], wmax[3]));

    float ev[8];
    float locsum = 0.f;
#pragma unroll
    for (int k = 0; k < 8; ++k) {
        float e = (sv[k] == -INFINITY) ? 0.f : expf(sv[k] - gmax);
        ev[k] = e;
        locsum += e;
    }
    for (int o = 1; o < 64; o <<= 1) locsum += __shfl_xor(locsum, o);
    if (lane == 0) wsumr[wave] = locsum;
    __syncthreads();
    float inv = 1.f / (wsumr[0] + wsumr[1] + wsumr[2] + wsumr[3]);
#pragma unroll
    for (int k = 0; k < 8; ++k) ex[t + k * 256] = ev[k] * inv;
    __syncthreads();

    // --- weighted sum over this block's s-chunk (unroll x4, 4 acc pairs) ---
    int s0 = ch * CHS;
    long long send_ll = (long long)(s0 + CHS);
    if (send_ll > len) send_ll = len;
    int send = (int)send_ll;

    const float* xbase = X + ((size_t)b * STEP) * HIDDEN + 2 * t;
    float2 a0v = {0.f, 0.f}, a1v = {0.f, 0.f};
    float2 a2v = {0.f, 0.f}, a3v = {0.f, 0.f};
    int s = s0;
    for (; s + 4 <= send; s += 4) {
        float w0 = ex[s], w1 = ex[s + 1], w2 = ex[s + 2], w3 = ex[s + 3];
        float2 x0 = *(const float2*)(xbase + (size_t)s * HIDDEN);
        float2 x1 = *(const float2*)(xbase + (size_t)(s + 1) * HIDDEN);
        float2 x2 = *(const float2*)(xbase + (size_t)(s + 2) * HIDDEN);
        float2 x3 = *(const float2*)(xbase + (size_t)(s + 3) * HIDDEN);
        a0v.x = fmaf(w0, x0.x, a0v.x); a0v.y = fmaf(w0, x0.y, a0v.y);
        a1v.x = fmaf(w1, x1.x, a1v.x); a1v.y = fmaf(w1, x1.y, a1v.y);
        a2v.x = fmaf(w2, x2.x, a2v.x); a2v.y = fmaf(w2, x2.y, a2v.y);
        a3v.x = fmaf(w3, x3.x, a3v.x); a3v.y = fmaf(w3, x3.y, a3v.y);
    }
    for (; s < send; ++s) {
        float w0 = ex[s];
        float2 x0 = *(const float2*)(xbase + (size_t)s * HIDDEN);
        a0v.x = fmaf(w0, x0.x, a0v.x); a0v.y = fmaf(w0, x0.y, a0v.y);
    }
    float2 acc = {(a0v.x + a1v.x) + (a2v.x + a3v.x),
                  (a0v.y + a1v.y) + (a2v.y + a3v.y)};
    float* prow = partial + ((size_t)b * NCH + ch) * HIDDEN;
    *(float2*)(prow + 2 * t) = acc;      // skipped chunks write zeros
}

// K3: out[b,h] = sum_ch partial[b,ch,h]
__global__ __launch_bounds__(256) void finalize_kernel(
    const float* __restrict__ partial, float* __restrict__ out)
{
    int b = blockIdx.x;
    int t = threadIdx.x;
    float2 a = {0.f, 0.f};
#pragma unroll
    for (int ch = 0; ch < NCH; ++ch) {
        const float* prow = partial + ((size_t)b * NCH + ch) * HIDDEN;
        float2 v = *(const float2*)(prow + 2 * t);
        a.x += v.x;
        a.y += v.y;
    }
    *(float2*)(out + (size_t)b * HIDDEN + 2 * t) = a;
}

extern "C" void kernel_launch(void* const* d_in, const int* in_sizes, int n_in,
                              void* d_out, int out_size, void* d_ws, size_t ws_size,
                              hipStream_t stream) {
    const float* X    = (const float*)d_in[0];
    const int*   lens = (const int*)d_in[1];   // dtype sniffed on device
    const float* W    = (const float*)d_in[2];
    const float* bias = (const float*)d_in[3];
    const float* ctx  = (const float*)d_in[4];
    float* out = (float*)d_out;

    char* ws = (char*)d_ws;
    float* sp      = (float*)ws;                    // [2][B*S] = 512 KB
    float* partial = (float*)(ws + 512 * 1024);     // 2 MB (NCH=32)
    short* wglds   = (short*)(ws + 2560 * 1024);    // 512 KB pre-swizzled W-hi
    int*   ctr     = (int*)(ws + 3072 * 1024);      // work-queue counter

    wsplit_kernel<<<dim3(ATTEN), 512, 0, stream>>>(W, wglds, ctr);
    scores_mfma_kernel<<<dim3(NBLOCKS), THREADS, 0, stream>>>(
        X, lens, wglds, bias, ctx, sp, ctr);
    wsum_kernel<<<dim3(NCH, BATCH), 256, 0, stream>>>(
        X, lens, sp, sp + (size_t)BATCH * STEP, partial);
    finalize_kernel<<<dim3(BATCH), 256, 0, stream>>>(partial, out);
}

// Round 24
// 74.949 us; speedup vs baseline: 1.1214x; 1.1214x over previous
//
#include <hip/hip_runtime.h>
#include <hip/hip_bf16.h>
#include <math.h>

#define HIDDEN 512
#define ATTEN  512
#define BATCH  32
#define STEP   2048

#define BM 128                // rows per tile
#define BN 256                // atten cols per tile (2 N-slices)
#define NS (ATTEN / BN)       // 2
#define BK 32                 // K tile
#define NT (HIDDEN / BK)      // 16 K-tiles
#define THREADS 512           // 8 waves: 2(M) x 4(N), wave tile 64x64
#define NTILES (BATCH * (STEP / BM) * NS)   // 1024 work items
#define NBLOCKS 512           // persistent blocks: 2/CU, all resident

#define NCH 32                // s-chunks in weighted-sum kernel
#define CHS (STEP / NCH)      // 64

typedef __attribute__((ext_vector_type(8))) short bf16x8;
typedef __attribute__((ext_vector_type(4))) float f32x4;

// batch_lens may arrive as int64 (reference dtype) or int32 (jax without x64).
// Values >= 1, so int32-view index 1 == 0 iff the buffer is int64.
__device__ __forceinline__ long long load_len(const int* lens_raw, int b) {
    bool is64 = (lens_raw[1] == 0);
    if (is64) return ((const long long*)lens_raw)[b];
    return (long long)lens_raw[b];
}

__device__ __forceinline__ short f2bf(float x) {        // RNE fp32 -> bf16 bits
    unsigned u = __float_as_uint(x);
    unsigned r = (u + 0x7FFFu + ((u >> 16) & 1u)) >> 16;
    return (short)r;
}

__device__ __forceinline__ float fast_tanh(float x) {
    float e = __expf(2.0f * x);         // saturates correctly at +-inf
    return 1.0f - 2.0f / (e + 1.0f);
}

// K0: pre-swizzled bf16-HI-only W (R9-proven layout) + work-counter reset.
// Per N-slice ns, K-tile kt: col-pair r2=c>>1 owns a 128B LDS row = 8 slots
// of 16B; slot8 = ((c&1)*4 + s) ^ (r2&7). global chunk n = r2*8 + slot8.
// wglds[((ns*16+kt)*1024 + n)*8 + j], 512 KB total.
__global__ __launch_bounds__(512) void wsplit_kernel(
    const float* __restrict__ W, short* __restrict__ wglds, int* __restrict__ ctr)
{
    if (blockIdx.x == 0 && threadIdx.x == 0) *ctr = 0;   // reset work queue
    int a = blockIdx.x;       // 0..511  (atten col)
    int h = threadIdx.x;      // 0..511  (hidden = k)
    float v = W[(size_t)h * ATTEN + a];
    short hi = f2bf(v);
    int ns = a >> 8, c = a & 255;
    int kt = h >> 5, s = (h >> 3) & 3, j = h & 7;
    int r2 = c >> 1;
    int slot8 = (((c & 1) << 2) | s) ^ (r2 & 7);
    size_t tb = ((size_t)ns * NT + kt) * 1024;
    wglds[(tb + (size_t)r2 * 8 + slot8) * 8 + j] = hi;
}

// K1: persistent-block scores. 512 blocks (2/CU), atomic work queue.
// R14/R19 VERBATIM (best measured): sync-only two-barrier body, 1-term bf16
// (xh*wh), X prefetch one tile ahead, kt-stagger.
__global__ __launch_bounds__(THREADS, 4) void scores_mfma_kernel(
    const float* __restrict__ X,        // [B*S*H] fp32
    const int*   __restrict__ lens_raw,
    const short* __restrict__ wglds,    // pre-swizzled bf16-hi W
    const float* __restrict__ bias,
    const float* __restrict__ ctx,
    float* __restrict__ scores_part,    // [NS][B*S]
    int* __restrict__ ctr)
{
    __shared__ char smem[32 * 1024];
    char* const At = smem;              // 16 KB: X-hi, swizzled
    char* const Bt = smem + 16 * 1024;  // 16 KB: W-hi, pair-swizzled
    __shared__ int widx;

    int t = threadIdx.x;
    int wave = t >> 6, lane = t & 63;
    int wrow = wave >> 2, wcol = wave & 3;      // 2 x 4 wave grid
    int l15 = lane & 15, l4 = lane >> 4;
    int ar = t >> 2, aq = t & 3;                // A staging: row, k-subslot
    int wvuni16 = (t & ~63) * 16;               // wave-uniform LDS byte base

    for (;;) {
        __syncthreads();                 // guards widx + LDS reuse across tiles
        if (t == 0) widx = atomicAdd(ctr, 1);
        __syncthreads();
        int idx = widx;
        if (idx >= NTILES) break;

        int ns = idx & 1;                // ns fastest: consecutive grabs share X
        int mt = idx >> 1;
        int b  = mt >> 4;                // 16 tiles per batch (BM=128)
        int s0 = (mt & 15) * BM;
        long long len = load_len(lens_raw, b);
        if ((long long)s0 >= len) continue;

        int ko = (idx * 7) & (NT - 1);   // K-loop stagger (sum order-free)

        const float* xrow = X + ((size_t)b * STEP + s0 + ar) * HIDDEN + aq * 8;
        const short* wbase = wglds + (size_t)ns * NT * 1024 * 8;

        f32x4 acc[4][4];
#pragma unroll
        for (int mi = 0; mi < 4; ++mi)
#pragma unroll
            for (int ni = 0; ni < 4; ++ni)
                acc[mi][ni] = (f32x4){0.f, 0.f, 0.f, 0.f};

        float4 px0, px1;                 // X prefetch (one tile ahead)

#define PXLOAD(KG)                                                           \
    do {                                                                     \
        px0 = *(const float4*)(xrow + (KG) * BK);                            \
        px1 = *(const float4*)(xrow + (KG) * BK + 4);                        \
    } while (0)

#define BISSUE(KG)                                                           \
    do {                                                                     \
        _Pragma("unroll")                                                    \
        for (int i = 0; i < 2; ++i) {                                        \
            const short* g = wbase + ((size_t)(KG) * 1024 + i * 512 + t) * 8;\
            char* l = Bt + i * 512 * 16 + wvuni16;                           \
            __builtin_amdgcn_global_load_lds(                                \
                (const __attribute__((address_space(1))) unsigned int*)g,    \
                (__attribute__((address_space(3))) unsigned int*)l,          \
                16, 0, 0);                                                   \
        }                                                                    \
    } while (0)

// 1-term: convert px -> bf16-hi only, swizzled ds_write into At
#define AWRITE()                                                             \
    do {                                                                     \
        float xs[8] = {px0.x, px0.y, px0.z, px0.w, px1.x, px1.y, px1.z, px1.w};\
        bf16x8 hv;                                                           \
        _Pragma("unroll")                                                    \
        for (int j = 0; j < 8; ++j) hv[j] = f2bf(xs[j]);                     \
        int rx = ar & 7;                                                     \
        *(bf16x8*)(At + ar * 128 + (((aq) ^ rx) << 4)) = hv;                 \
    } while (0)

// 1 term: xh*wh (bf16 x bf16, fp32 accumulate)
#define COMPUTE()                                                            \
    do {                                                                     \
        bf16x8 ah[4];                                                        \
        _Pragma("unroll")                                                    \
        for (int mi = 0; mi < 4; ++mi) {                                     \
            int row = wrow * 64 + mi * 16 + l15;                             \
            int rx = row & 7;                                                \
            ah[mi] = *(const bf16x8*)(At + row * 128 + ((l4 ^ rx) << 4));    \
        }                                                                    \
        _Pragma("unroll")                                                    \
        for (int ni = 0; ni < 4; ++ni) {                                     \
            int col = wcol * 64 + ni * 16 + l15;                             \
            int r2 = col >> 1;                                               \
            int sl = ((((col & 1) << 2) | l4) ^ (r2 & 7));                   \
            bf16x8 bh = *(const bf16x8*)(Bt + r2 * 128 + (sl << 4));         \
            _Pragma("unroll")                                                \
            for (int mi = 0; mi < 4; ++mi) {                                 \
                acc[mi][ni] = __builtin_amdgcn_mfma_f32_16x16x32_bf16(       \
                    ah[mi], bh, acc[mi][ni], 0, 0, 0);                       \
            }                                                                \
        }                                                                    \
    } while (0)

        // prologue: stage tile ko (X conv + B-DMA), full drain
        int kcur = ko;
        PXLOAD(kcur);
        BISSUE(kcur);
        AWRITE();                        // compiler waits px vmcnt
        __syncthreads();                 // drains DMA + ds_writes

#pragma unroll
        for (int kt = 0; kt < NT; ++kt) {
            int knxt = (kcur + 1) & (NT - 1);
            if (kt + 1 < NT) PXLOAD(knxt);   // X(next) flies under COMPUTE
            COMPUTE();
            __syncthreads();                 // all waves done reading At/Bt
            if (kt + 1 < NT) {
                BISSUE(knxt);                // B-DMA (L2-resident W)
                AWRITE();                    // convert px(next) while DMA flies
                __syncthreads();             // full drain: tiles ready
            }
            kcur = knxt;
        }
#undef PXLOAD
#undef BISSUE
#undef AWRITE
#undef COMPUTE

        // fused epilogue: tanh(acc+bias)*ctx over this slice's 256 cols
        float bi[4], ci[4];
#pragma unroll
        for (int ni = 0; ni < 4; ++ni) {
            int a = ns * BN + wcol * 64 + ni * 16 + l15;
            bi[ni] = bias[a];
            ci[ni] = ctx[a];
        }
        __syncthreads();                 // all waves done with LDS tiles
        float* partial = (float*)At;     // [4 wcol][BM]
#pragma unroll
        for (int mi = 0; mi < 4; ++mi) {
#pragma unroll
            for (int reg = 0; reg < 4; ++reg) {
                float s = 0.f;
#pragma unroll
                for (int ni = 0; ni < 4; ++ni)
                    s += fast_tanh(acc[mi][ni][reg] + bi[ni]) * ci[ni];
                s += __shfl_xor(s, 1);
                s += __shfl_xor(s, 2);
                s += __shfl_xor(s, 4);
                s += __shfl_xor(s, 8);
                if (l15 == 0) {
                    int row = wrow * 64 + mi * 16 + l4 * 4 + reg;  // C/D layout
                    partial[wcol * BM + row] = s;
                }
            }
        }
        __syncthreads();
        if (t < BM) {
            float v = partial[0 * BM + t] + partial[1 * BM + t]
                    + partial[2 * BM + t] + partial[3 * BM + t];
            scores_part[((size_t)ns * BATCH + b) * STEP + s0 + t] = v;
        }
    }
}

// K2 (fused softmax + weighted sum): each block recomputes the row softmax
// deterministically (identical reduction tree in every block -> identical
// result), stores exp-weights in LDS, then accumulates its s-chunk.
// partial[b,ch,h] = sum_{s in chunk, s<len} atten[b,s] * X[b,s,h]
__global__ __launch_bounds__(256) void wsum_kernel(
    const float* __restrict__ X, const int* __restrict__ lens_raw,
    const float* __restrict__ p0, const float* __restrict__ p1,
    float* __restrict__ partial)
{
    __shared__ float wmax[4], wsumr[4];
    __shared__ float ex[STEP];          // 8 KB: attention weights
    int ch = blockIdx.x;
    int b  = blockIdx.y;
    long long len = load_len(lens_raw, b);
    int t = threadIdx.x;

    // --- replicated masked softmax (exact tree of the old K2) ---
    const float* r0 = p0 + (size_t)b * STEP;
    const float* r1 = p1 + (size_t)b * STEP;
    float sv[STEP / 256];
    float locmax = -INFINITY;
#pragma unroll
    for (int k = 0; k < 8; ++k) {
        int s = t + k * 256;
        float v = ((long long)s < len) ? (r0[s] + r1[s]) : -INFINITY;
        sv[k] = v;
        locmax = fmaxf(locmax, v);
    }
    for (int o = 1; o < 64; o <<= 1) locmax = fmaxf(locmax, __shfl_xor(locmax, o));
    int wave = t >> 6, lane = t & 63;
    if (lane == 0) wmax[wave] = locmax;
    __syncthreads();
    float gmax = fmaxf(fmaxf(wmax[0], wmax[1]), fmaxf(wmax[2], wmax[3]));

    float ev[8];
    float locsum = 0.f;
#pragma unroll
    for (int k = 0; k < 8; ++k) {
        float e = (sv[k] == -INFINITY) ? 0.f : expf(sv[k] - gmax);
        ev[k] = e;
        locsum += e;
    }
    for (int o = 1; o < 64; o <<= 1) locsum += __shfl_xor(locsum, o);
    if (lane == 0) wsumr[wave] = locsum;
    __syncthreads();
    float inv = 1.f / (wsumr[0] + wsumr[1] + wsumr[2] + wsumr[3]);
#pragma unroll
    for (int k = 0; k < 8; ++k) ex[t + k * 256] = ev[k] * inv;
    __syncthreads();

    // --- weighted sum over this block's s-chunk (unroll x4, 4 acc pairs) ---
    int s0 = ch * CHS;
    long long send_ll = (long long)(s0 + CHS);
    if (send_ll > len) send_ll = len;
    int send = (int)send_ll;

    const float* xbase = X + ((size_t)b * STEP) * HIDDEN + 2 * t;
    float2 a0v = {0.f, 0.f}, a1v = {0.f, 0.f};
    float2 a2v = {0.f, 0.f}, a3v = {0.f, 0.f};
    int s = s0;
    for (; s + 4 <= send; s += 4) {
        float w0 = ex[s], w1 = ex[s + 1], w2 = ex[s + 2], w3 = ex[s + 3];
        float2 x0 = *(const float2*)(xbase + (size_t)s * HIDDEN);
        float2 x1 = *(const float2*)(xbase + (size_t)(s + 1) * HIDDEN);
        float2 x2 = *(const float2*)(xbase + (size_t)(s + 2) * HIDDEN);
        float2 x3 = *(const float2*)(xbase + (size_t)(s + 3) * HIDDEN);
        a0v.x = fmaf(w0, x0.x, a0v.x); a0v.y = fmaf(w0, x0.y, a0v.y);
        a1v.x = fmaf(w1, x1.x, a1v.x); a1v.y = fmaf(w1, x1.y, a1v.y);
        a2v.x = fmaf(w2, x2.x, a2v.x); a2v.y = fmaf(w2, x2.y, a2v.y);
        a3v.x = fmaf(w3, x3.x, a3v.x); a3v.y = fmaf(w3, x3.y, a3v.y);
    }
    for (; s < send; ++s) {
        float w0 = ex[s];
        float2 x0 = *(const float2*)(xbase + (size_t)s * HIDDEN);
        a0v.x = fmaf(w0, x0.x, a0v.x); a0v.y = fmaf(w0, x0.y, a0v.y);
    }
    float2 acc = {(a0v.x + a1v.x) + (a2v.x + a3v.x),
                  (a0v.y + a1v.y) + (a2v.y + a3v.y)};
    float* prow = partial + ((size_t)b * NCH + ch) * HIDDEN;
    *(float2*)(prow + 2 * t) = acc;      // skipped chunks write zeros
}

// K3: out[b,h] = sum_ch partial[b,ch,h]
__global__ __launch_bounds__(256) void finalize_kernel(
    const float* __restrict__ partial, float* __restrict__ out)
{
    int b = blockIdx.x;
    int t = threadIdx.x;
    float2 a = {0.f, 0.f};
#pragma unroll
    for (int ch = 0; ch < NCH; ++ch) {
        const float* prow = partial + ((size_t)b * NCH + ch) * HIDDEN;
        float2 v = *(const float2*)(prow + 2 * t);
        a.x += v.x;
        a.y += v.y;
    }
    *(float2*)(out + (size_t)b * HIDDEN + 2 * t) = a;
}

extern "C" void kernel_launch(void* const* d_in, const int* in_sizes, int n_in,
                              void* d_out, int out_size, void* d_ws, size_t ws_size,
                              hipStream_t stream) {
    const float* X    = (const float*)d_in[0];
    const int*   lens = (const int*)d_in[1];   // dtype sniffed on device
    const float* W    = (const float*)d_in[2];
    const float* bias = (const float*)d_in[3];
    const float* ctx  = (const float*)d_in[4];
    float* out = (float*)d_out;

    char* ws = (char*)d_ws;
    float* sp      = (float*)ws;                    // [2][B*S] = 512 KB
    float* partial = (float*)(ws + 512 * 1024);     // 2 MB (NCH=32)
    short* wglds   = (short*)(ws + 2560 * 1024);    // 512 KB pre-swizzled W-hi
    int*   ctr     = (int*)(ws + 3072 * 1024);      // work-queue counter

    wsplit_kernel<<<dim3(ATTEN), 512, 0, stream>>>(W, wglds, ctr);
    scores_mfma_kernel<<<dim3(NBLOCKS), THREADS, 0, stream>>>(
        X, lens, wglds, bias, ctx, sp, ctr);
    wsum_kernel<<<dim3(NCH, BATCH), 256, 0, stream>>>(
        X, lens, sp, sp + (size_t)BATCH * STEP, partial);
    finalize_kernel<<<dim3(BATCH), 256, 0, stream>>>(partial, out);
}